// Round 1
// baseline (295.862 us; speedup 1.0000x reference)
//
#include <hip/hip_runtime.h>
#include <math.h>

#define N 4096
#define D 512
#define BM 128
#define BN 128
#define BK 32
#define NSPLIT (N / BN)   // 32 column splits
#define LDSTR 132         // padded LDS row stride (floats): 16B-aligned, limits conflicts

// ---------------- Kernel A: sq[i] = sum(x_i^2), one wave per row ----------------
__global__ __launch_bounds__(256) void k_sq(const float* __restrict__ X,
                                            float* __restrict__ sq) {
    const int wave = threadIdx.x >> 6;
    const int lane = threadIdx.x & 63;
    const int row = blockIdx.x * 4 + wave;
    const float* xr = X + (size_t)row * D + lane * 8;
    float4 v0 = *(const float4*)(xr);
    float4 v1 = *(const float4*)(xr + 4);
    float s = v0.x * v0.x + v0.y * v0.y + v0.z * v0.z + v0.w * v0.w +
              v1.x * v1.x + v1.y * v1.y + v1.z * v1.z + v1.w * v1.w;
#pragma unroll
    for (int off = 32; off >= 1; off >>= 1) s += __shfl_xor(s, off);
    if (lane == 0) sq[row] = s;
}

// ---------------- Kernel B: tiled gram + fused masked argmax/argmin ----------------
// Block computes a 128x128 tile of pd = sqrt(max(sq_i + sq_j - 2*dot, 0)),
// tracks hardest positive (max pd, same label, j!=i) and hardest negative
// (min pd, diff label) per row over this tile's 128 columns; writes partials.
__global__ __launch_bounds__(256) void k_tile(
    const float* __restrict__ X, const int* __restrict__ labels,
    const float* __restrict__ sq,
    float* __restrict__ pmaxv, int* __restrict__ pmaxi,
    float* __restrict__ pminv, int* __restrict__ pmini) {
    __shared__ float As[BK][LDSTR];   // As[k][m] = A[row0+m][k0+k]
    __shared__ float Bs[BK][LDSTR];
    __shared__ float sqr[BM], sqc[BN];
    __shared__ int labr[BM], labc[BN];

    const int ct = blockIdx.x, rt = blockIdx.y;
    const int row0 = rt * BM, col0 = ct * BN;
    const int tid = threadIdx.x;
    const int tx = tid & 15, ty = tid >> 4;

    if (tid < BM) {
        sqr[tid] = sq[row0 + tid];
        labr[tid] = labels[row0 + tid];
    } else {
        int t = tid - BM;
        sqc[t] = sq[col0 + t];
        labc[t] = labels[col0 + t];
    }

    float acc[8][8];
#pragma unroll
    for (int i = 0; i < 8; ++i)
#pragma unroll
        for (int j = 0; j < 8; ++j) acc[i][j] = 0.f;

    for (int k0 = 0; k0 < D; k0 += BK) {
        __syncthreads();  // protect LDS reuse across iterations (and labels on iter 0)
#pragma unroll
        for (int p = 0; p < 4; ++p) {
            int f = tid + 256 * p;
            int m = f >> 3, kq = f & 7;
            float4 va = *(const float4*)(&X[(size_t)(row0 + m) * D + k0 + kq * 4]);
            As[kq * 4 + 0][m] = va.x;
            As[kq * 4 + 1][m] = va.y;
            As[kq * 4 + 2][m] = va.z;
            As[kq * 4 + 3][m] = va.w;
            float4 vb = *(const float4*)(&X[(size_t)(col0 + m) * D + k0 + kq * 4]);
            Bs[kq * 4 + 0][m] = vb.x;
            Bs[kq * 4 + 1][m] = vb.y;
            Bs[kq * 4 + 2][m] = vb.z;
            Bs[kq * 4 + 3][m] = vb.w;
        }
        __syncthreads();
#pragma unroll 8
        for (int k = 0; k < BK; ++k) {
            float4 a0 = *(const float4*)&As[k][ty * 8];
            float4 a1 = *(const float4*)&As[k][ty * 8 + 4];
            float4 b0 = *(const float4*)&Bs[k][tx * 8];
            float4 b1 = *(const float4*)&Bs[k][tx * 8 + 4];
            float a[8] = {a0.x, a0.y, a0.z, a0.w, a1.x, a1.y, a1.z, a1.w};
            float b[8] = {b0.x, b0.y, b0.z, b0.w, b1.x, b1.y, b1.z, b1.w};
#pragma unroll
            for (int i = 0; i < 8; ++i)
#pragma unroll
                for (int j = 0; j < 8; ++j) acc[i][j] += a[i] * b[j];
        }
    }

    // ---- epilogue: per-thread candidates over its 8x8 sub-tile ----
    float pmv[8], nmv[8];
    int pmi_[8], nmi_[8];
#pragma unroll
    for (int i = 0; i < 8; ++i) {
        pmv[i] = -INFINITY;
        pmi_[i] = 0x7fffffff;
        nmv[i] = INFINITY;
        nmi_[i] = 0x7fffffff;
    }

#pragma unroll
    for (int ii = 0; ii < 8; ++ii) {
        const int rloc = ty * 8 + ii;
        const int r = row0 + rloc;
        const int lr = labr[rloc];
        const float sr = sqr[rloc];
#pragma unroll
        for (int jj = 0; jj < 8; ++jj) {
            const int cloc = tx * 8 + jj;
            const int c = col0 + cloc;
            float d2 = sr + sqc[cloc] - 2.f * acc[ii][jj];
            float pd = sqrtf(fmaxf(d2, 0.f));
            bool same = (lr == labc[cloc]);
            if (c == r) continue;  // exclude self (eye)
            if (same) {
                // argmax, first occurrence on ties (smaller index wins)
                if (pd > pmv[ii] || (pd == pmv[ii] && c < pmi_[ii])) {
                    pmv[ii] = pd;
                    pmi_[ii] = c;
                }
            } else {
                if (pd < nmv[ii] || (pd == nmv[ii] && c < nmi_[ii])) {
                    nmv[ii] = pd;
                    nmi_[ii] = c;
                }
            }
        }
    }

    // ---- reduce across the 16 lanes sharing each row (tx dimension) ----
#pragma unroll
    for (int ii = 0; ii < 8; ++ii) {
#pragma unroll
        for (int s = 1; s < 16; s <<= 1) {
            float ov = __shfl_xor(pmv[ii], s);
            int oi = __shfl_xor(pmi_[ii], s);
            if (ov > pmv[ii] || (ov == pmv[ii] && oi < pmi_[ii])) {
                pmv[ii] = ov;
                pmi_[ii] = oi;
            }
            float ov2 = __shfl_xor(nmv[ii], s);
            int oi2 = __shfl_xor(nmi_[ii], s);
            if (ov2 < nmv[ii] || (ov2 == nmv[ii] && oi2 < nmi_[ii])) {
                nmv[ii] = ov2;
                nmi_[ii] = oi2;
            }
        }
        if (tx == 0) {
            const int r = row0 + ty * 8 + ii;
            pmaxv[(size_t)r * NSPLIT + ct] = pmv[ii];
            pmaxi[(size_t)r * NSPLIT + ct] = pmi_[ii];
            pminv[(size_t)r * NSPLIT + ct] = nmv[ii];
            pmini[(size_t)r * NSPLIT + ct] = nmi_[ii];
        }
    }
}

// ---------------- Kernel C: per-row final reduce + exact triplet distance ----------------
__global__ __launch_bounds__(256) void k_final(
    const float* __restrict__ X,
    const float* __restrict__ pmaxv, const int* __restrict__ pmaxi,
    const float* __restrict__ pminv, const int* __restrict__ pmini,
    float* __restrict__ bsum, int* __restrict__ bcnt) {
    __shared__ float ssum[4];
    __shared__ int scnt[4];
    const int wave = threadIdx.x >> 6, lane = threadIdx.x & 63;
    const int row = blockIdx.x * 4 + wave;

    float pv = -INFINITY, nv = INFINITY;
    int pi = 0x7fffffff, ni = 0x7fffffff;
    if (lane < NSPLIT) {
        pv = pmaxv[(size_t)row * NSPLIT + lane];
        pi = pmaxi[(size_t)row * NSPLIT + lane];
        nv = pminv[(size_t)row * NSPLIT + lane];
        ni = pmini[(size_t)row * NSPLIT + lane];
    }
#pragma unroll
    for (int s = 1; s < 32; s <<= 1) {  // reduce within lanes 0..31
        float ov = __shfl_xor(pv, s);
        int oi = __shfl_xor(pi, s);
        if (ov > pv || (ov == pv && oi < pi)) {
            pv = ov;
            pi = oi;
        }
        float ov2 = __shfl_xor(nv, s);
        int oi2 = __shfl_xor(ni, s);
        if (ov2 < nv || (ov2 == nv && oi2 < ni)) {
            nv = ov2;
            ni = oi2;
        }
    }
    pv = __shfl(pv, 0);
    pi = __shfl(pi, 0);
    nv = __shfl(nv, 0);
    ni = __shfl(ni, 0);
    const bool valid = (pv != -INFINITY) && (nv != INFINITY);
    const int pidx = (pi == 0x7fffffff) ? 0 : pi;
    const int nidx = (ni == 0x7fffffff) ? 0 : ni;

    // exact recompute: d = sqrt(sum((a - b + 1e-6)^2)) as in the reference
    const float* xa = X + (size_t)row * D + lane * 8;
    const float* xp = X + (size_t)pidx * D + lane * 8;
    const float* xn = X + (size_t)nidx * D + lane * 8;
    float4 a0 = *(const float4*)(xa), a1 = *(const float4*)(xa + 4);
    float4 p0 = *(const float4*)(xp), p1 = *(const float4*)(xp + 4);
    float4 n0 = *(const float4*)(xn), n1 = *(const float4*)(xn + 4);
    float sap = 0.f, san = 0.f;
    {
        float d;
        d = a0.x - p0.x + 1e-6f; sap += d * d;
        d = a0.y - p0.y + 1e-6f; sap += d * d;
        d = a0.z - p0.z + 1e-6f; sap += d * d;
        d = a0.w - p0.w + 1e-6f; sap += d * d;
        d = a1.x - p1.x + 1e-6f; sap += d * d;
        d = a1.y - p1.y + 1e-6f; sap += d * d;
        d = a1.z - p1.z + 1e-6f; sap += d * d;
        d = a1.w - p1.w + 1e-6f; sap += d * d;
        d = a0.x - n0.x + 1e-6f; san += d * d;
        d = a0.y - n0.y + 1e-6f; san += d * d;
        d = a0.z - n0.z + 1e-6f; san += d * d;
        d = a0.w - n0.w + 1e-6f; san += d * d;
        d = a1.x - n1.x + 1e-6f; san += d * d;
        d = a1.y - n1.y + 1e-6f; san += d * d;
        d = a1.z - n1.z + 1e-6f; san += d * d;
        d = a1.w - n1.w + 1e-6f; san += d * d;
    }
#pragma unroll
    for (int off = 32; off >= 1; off >>= 1) {
        sap += __shfl_xor(sap, off);
        san += __shfl_xor(san, off);
    }
    if (lane == 0) {
        float d_ap = sqrtf(sap), d_an = sqrtf(san);
        float per = valid ? fmaxf(d_ap - d_an + 1.0f, 0.f) : 0.f;
        ssum[wave] = per;
        scnt[wave] = valid ? 1 : 0;
    }
    __syncthreads();
    if (threadIdx.x == 0) {
        bsum[blockIdx.x] = ssum[0] + ssum[1] + ssum[2] + ssum[3];
        bcnt[blockIdx.x] = scnt[0] + scnt[1] + scnt[2] + scnt[3];
    }
}

// ---------------- Kernel D: deterministic scalar reduce ----------------
__global__ __launch_bounds__(256) void k_out(const float* __restrict__ bsum,
                                             const int* __restrict__ bcnt,
                                             float* __restrict__ out) {
    __shared__ float ss[256];
    __shared__ int sc[256];
    const int t = threadIdx.x;
    float s = 0.f;
    int c = 0;
    for (int i = t; i < N / 4; i += 256) {
        s += bsum[i];
        c += bcnt[i];
    }
    ss[t] = s;
    sc[t] = c;
    __syncthreads();
    for (int off = 128; off >= 1; off >>= 1) {
        if (t < off) {
            ss[t] += ss[t + off];
            sc[t] += sc[t + off];
        }
        __syncthreads();
    }
    if (t == 0) out[0] = ss[0] / (float)max(sc[0], 1);
}

extern "C" void kernel_launch(void* const* d_in, const int* in_sizes, int n_in,
                              void* d_out, int out_size, void* d_ws, size_t ws_size,
                              hipStream_t stream) {
    const float* X = (const float*)d_in[0];
    const int* labels = (const int*)d_in[1];
    float* ws = (float*)d_ws;

    float* sq = ws;                               // N floats
    float* pmaxv = ws + N;                        // N*NSPLIT floats
    float* pminv = pmaxv + (size_t)N * NSPLIT;    // N*NSPLIT floats
    int* pmaxi = (int*)(pminv + (size_t)N * NSPLIT);
    int* pmini = pmaxi + (size_t)N * NSPLIT;
    float* bsum = (float*)(pmini + (size_t)N * NSPLIT);  // N/4 floats
    int* bcnt = (int*)(bsum + N / 4);
    float* out = (float*)d_out;

    k_sq<<<N / 4, 256, 0, stream>>>(X, sq);
    k_tile<<<dim3(NSPLIT, N / BM), 256, 0, stream>>>(X, labels, sq, pmaxv, pmaxi,
                                                     pminv, pmini);
    k_final<<<N / 4, 256, 0, stream>>>(X, pmaxv, pmaxi, pminv, pmini, bsum, bcnt);
    k_out<<<1, 256, 0, stream>>>(bsum, bcnt, out);
}

// Round 3
// 178.771 us; speedup vs baseline: 1.6550x; 1.6550x over previous
//
#include <hip/hip_runtime.h>
#include <math.h>

#define N 4096
#define D 512
#define NS2 64            // column splits (N / 64)
#define NT 48             // K steps: 3 terms x (512/32)

typedef __attribute__((ext_vector_type(8))) short short8;
typedef __attribute__((ext_vector_type(8))) unsigned short ushort8;
typedef __attribute__((ext_vector_type(4))) float f32x4;

// RNE float -> bf16 bits (no NaN handling needed: inputs are finite)
static __device__ __forceinline__ unsigned short f2bf(float f) {
    unsigned u = __float_as_uint(f);
    u = (u + 0x7fffu + ((u >> 16) & 1u)) >> 16;
    return (unsigned short)u;
}
static __device__ __forceinline__ float bf2f(unsigned short b) {
    return __uint_as_float(((unsigned)b) << 16);
}

// ---------------- Kernel A: split X into bf16 hi/lo and compute sq norms ----------------
// one wave per row (4 rows/block)
__global__ __launch_bounds__(256) void k_split_sq(const float* __restrict__ X,
                                                  unsigned short* __restrict__ Xhi,
                                                  unsigned short* __restrict__ Xlo,
                                                  float* __restrict__ sq) {
    const int wave = threadIdx.x >> 6;
    const int lane = threadIdx.x & 63;
    const int row = blockIdx.x * 4 + wave;
    const float* xr = X + (size_t)row * D + lane * 8;
    float4 v0 = *(const float4*)(xr);
    float4 v1 = *(const float4*)(xr + 4);
    float v[8] = {v0.x, v0.y, v0.z, v0.w, v1.x, v1.y, v1.z, v1.w};
    ushort8 hv, lv;
    float s = 0.f;
#pragma unroll
    for (int j = 0; j < 8; ++j) {
        float f = v[j];
        unsigned short hb = f2bf(f);
        float hf = bf2f(hb);
        unsigned short lb = f2bf(f - hf);
        hv[j] = hb;
        lv[j] = lb;
        s += f * f;
    }
    *(ushort8*)(Xhi + (size_t)row * D + lane * 8) = hv;
    *(ushort8*)(Xlo + (size_t)row * D + lane * 8) = lv;
#pragma unroll
    for (int off = 32; off >= 1; off >>= 1) s += __shfl_xor(s, off);
    if (lane == 0) sq[row] = s;
}

// ---------------- Kernel B: bf16-split MFMA gram + fused masked argmax/argmin ----------------
// grid (32, 32); block 256 = 4 waves in 2x2; 128x128 output tile; BK=32.
__global__ __launch_bounds__(256) void k_tile_mfma(
    const unsigned short* __restrict__ Xhi, const unsigned short* __restrict__ Xlo,
    const int* __restrict__ labels, const float* __restrict__ sq,
    float* __restrict__ pmaxv, int* __restrict__ pmaxi,
    float* __restrict__ pminv, int* __restrict__ pmini) {
    __shared__ unsigned short As[128 * 32];   // [row][k], row stride 32 elems (64B)
    __shared__ unsigned short Bs[128 * 32];
    __shared__ float sqr[128], sqc[128];
    __shared__ int labr[128], labc[128];

    const int ct = blockIdx.x, rt = blockIdx.y;
    const int row0 = rt * 128, col0 = ct * 128;
    const int tid = threadIdx.x;
    const int w = tid >> 6, lane = tid & 63;
    const int wr = w >> 1, wc = w & 1;      // wave tile: rows wr*64, cols wc*64
    const int g = lane >> 4, c = lane & 15;

    if (tid < 128) {
        sqr[tid] = sq[row0 + tid];
        labr[tid] = labels[row0 + tid];
    } else {
        int t = tid - 128;
        sqc[t] = sq[col0 + t];
        labc[t] = labels[col0 + t];
    }

    f32x4 acc[4][4];
#pragma unroll
    for (int i = 0; i < 4; ++i)
#pragma unroll
        for (int j = 0; j < 4; ++j) acc[i][j] = (f32x4){0.f, 0.f, 0.f, 0.f};

    // staging: per wave 2 issues of 1KB each for A and for B
    const int srow = lane >> 2;         // 0..15
    const int scol = (lane & 3) * 8;    // 0,8,16,24

    const unsigned short* Aterm[3] = {Xhi, Xhi, Xlo};
    const unsigned short* Bterm[3] = {Xhi, Xlo, Xhi};

    for (int s = 0; s < NT; ++s) {
        const int t = s >> 4;
        const int k0 = (s & 15) * 32;
        const unsigned short* Ap = Aterm[t];
        const unsigned short* Bp = Bterm[t];
#pragma unroll
        for (int i = 0; i < 2; ++i) {
            const int r = (w * 2 + i) * 16 + srow;
            __builtin_amdgcn_global_load_lds(
                (const __attribute__((address_space(1))) unsigned int*)(Ap + (size_t)(row0 + r) * D + k0 + scol),
                (__attribute__((address_space(3))) unsigned int*)&As[(w * 2 + i) * 512],
                16, 0, 0);
            __builtin_amdgcn_global_load_lds(
                (const __attribute__((address_space(1))) unsigned int*)(Bp + (size_t)(col0 + r) * D + k0 + scol),
                (__attribute__((address_space(3))) unsigned int*)&Bs[(w * 2 + i) * 512],
                16, 0, 0);
        }
        __syncthreads();   // drains vmcnt: staged tile visible

        short8 af[4], bf[4];
#pragma unroll
        for (int i = 0; i < 4; ++i) {
            af[i] = *(const short8*)&As[(wr * 64 + i * 16 + c) * 32 + g * 8];
            bf[i] = *(const short8*)&Bs[(wc * 64 + i * 16 + c) * 32 + g * 8];
        }
#pragma unroll
        for (int i = 0; i < 4; ++i)
#pragma unroll
            for (int j = 0; j < 4; ++j)
                acc[i][j] = __builtin_amdgcn_mfma_f32_16x16x32_bf16(af[i], bf[j], acc[i][j], 0, 0, 0);
        __syncthreads();   // all waves done reading before next stage overwrites
    }

    // ---- fused epilogue: pd = sqrt(max(sq_i + sq_j - 2G, 0)); masked hardest pos/neg ----
    const int cs = ct * 2 + wc;  // column-split id, 0..63
#pragma unroll
    for (int i = 0; i < 4; ++i) {
#pragma unroll
        for (int q = 0; q < 4; ++q) {
            const int rloc = wr * 64 + i * 16 + g * 4 + q;
            const int r = row0 + rloc;
            const int lr = labr[rloc];
            const float sr = sqr[rloc];
            float pv = -INFINITY, nv = INFINITY;
            int pi = 0x7fffffff, ni = 0x7fffffff;
#pragma unroll
            for (int j = 0; j < 4; ++j) {
                const int cloc = wc * 64 + j * 16 + c;
                const int cg = col0 + cloc;
                float d2 = sr + sqc[cloc] - 2.f * acc[i][j][q];
                float pd = sqrtf(fmaxf(d2, 0.f));
                if (cg == r) continue;
                if (lr == labc[cloc]) {
                    if (pd > pv || (pd == pv && cg < pi)) { pv = pd; pi = cg; }
                } else {
                    if (pd < nv || (pd == nv && cg < ni)) { nv = pd; ni = cg; }
                }
            }
#pragma unroll
            for (int st = 1; st < 16; st <<= 1) {
                float ov = __shfl_xor(pv, st);
                int oi = __shfl_xor(pi, st);
                if (ov > pv || (ov == pv && oi < pi)) { pv = ov; pi = oi; }
                float ov2 = __shfl_xor(nv, st);
                int oi2 = __shfl_xor(ni, st);
                if (ov2 < nv || (ov2 == nv && oi2 < ni)) { nv = ov2; ni = oi2; }
            }
            if (c == 0) {
                pmaxv[(size_t)r * NS2 + cs] = pv;
                pmaxi[(size_t)r * NS2 + cs] = pi;
                pminv[(size_t)r * NS2 + cs] = nv;
                pmini[(size_t)r * NS2 + cs] = ni;
            }
        }
    }
}

// ---------------- Kernel C: per-row final reduce + exact triplet distance ----------------
__global__ __launch_bounds__(256) void k_final(
    const float* __restrict__ X,
    const float* __restrict__ pmaxv, const int* __restrict__ pmaxi,
    const float* __restrict__ pminv, const int* __restrict__ pmini,
    float* __restrict__ bsum, int* __restrict__ bcnt) {
    __shared__ float ssum[4];
    __shared__ int scnt[4];
    const int wave = threadIdx.x >> 6, lane = threadIdx.x & 63;
    const int row = blockIdx.x * 4 + wave;

    float pv = pmaxv[(size_t)row * NS2 + lane];
    int pi = pmaxi[(size_t)row * NS2 + lane];
    float nv = pminv[(size_t)row * NS2 + lane];
    int ni = pmini[(size_t)row * NS2 + lane];
#pragma unroll
    for (int s = 1; s < 64; s <<= 1) {
        float ov = __shfl_xor(pv, s);
        int oi = __shfl_xor(pi, s);
        if (ov > pv || (ov == pv && oi < pi)) { pv = ov; pi = oi; }
        float ov2 = __shfl_xor(nv, s);
        int oi2 = __shfl_xor(ni, s);
        if (ov2 < nv || (ov2 == nv && oi2 < ni)) { nv = ov2; ni = oi2; }
    }
    const bool valid = (pv != -INFINITY) && (nv != INFINITY);
    const int pidx = (pi == 0x7fffffff) ? 0 : pi;
    const int nidx = (ni == 0x7fffffff) ? 0 : ni;

    // exact recompute: d = sqrt(sum((a - b + 1e-6)^2)) per the reference
    const float* xa = X + (size_t)row * D + lane * 8;
    const float* xp = X + (size_t)pidx * D + lane * 8;
    const float* xn = X + (size_t)nidx * D + lane * 8;
    float4 a0 = *(const float4*)(xa), a1 = *(const float4*)(xa + 4);
    float4 p0 = *(const float4*)(xp), p1 = *(const float4*)(xp + 4);
    float4 n0 = *(const float4*)(xn), n1 = *(const float4*)(xn + 4);
    float sap = 0.f, san = 0.f;
    {
        float d;
        d = a0.x - p0.x + 1e-6f; sap += d * d;
        d = a0.y - p0.y + 1e-6f; sap += d * d;
        d = a0.z - p0.z + 1e-6f; sap += d * d;
        d = a0.w - p0.w + 1e-6f; sap += d * d;
        d = a1.x - p1.x + 1e-6f; sap += d * d;
        d = a1.y - p1.y + 1e-6f; sap += d * d;
        d = a1.z - p1.z + 1e-6f; sap += d * d;
        d = a1.w - p1.w + 1e-6f; sap += d * d;
        d = a0.x - n0.x + 1e-6f; san += d * d;
        d = a0.y - n0.y + 1e-6f; san += d * d;
        d = a0.z - n0.z + 1e-6f; san += d * d;
        d = a0.w - n0.w + 1e-6f; san += d * d;
        d = a1.x - n1.x + 1e-6f; san += d * d;
        d = a1.y - n1.y + 1e-6f; san += d * d;
        d = a1.z - n1.z + 1e-6f; san += d * d;
        d = a1.w - n1.w + 1e-6f; san += d * d;
    }
#pragma unroll
    for (int off = 32; off >= 1; off >>= 1) {
        sap += __shfl_xor(sap, off);
        san += __shfl_xor(san, off);
    }
    if (lane == 0) {
        float d_ap = sqrtf(sap), d_an = sqrtf(san);
        float per = valid ? fmaxf(d_ap - d_an + 1.0f, 0.f) : 0.f;
        ssum[wave] = per;
        scnt[wave] = valid ? 1 : 0;
    }
    __syncthreads();
    if (threadIdx.x == 0) {
        bsum[blockIdx.x] = ssum[0] + ssum[1] + ssum[2] + ssum[3];
        bcnt[blockIdx.x] = scnt[0] + scnt[1] + scnt[2] + scnt[3];
    }
}

// ---------------- Kernel D: deterministic scalar reduce ----------------
__global__ __launch_bounds__(256) void k_out(const float* __restrict__ bsum,
                                             const int* __restrict__ bcnt,
                                             float* __restrict__ out) {
    __shared__ float ss[256];
    __shared__ int sc[256];
    const int t = threadIdx.x;
    float s = 0.f;
    int c = 0;
    for (int i = t; i < N / 4; i += 256) {
        s += bsum[i];
        c += bcnt[i];
    }
    ss[t] = s;
    sc[t] = c;
    __syncthreads();
    for (int off = 128; off >= 1; off >>= 1) {
        if (t < off) {
            ss[t] += ss[t + off];
            sc[t] += sc[t + off];
        }
        __syncthreads();
    }
    if (t == 0) out[0] = ss[0] / (float)max(sc[0], 1);
}

extern "C" void kernel_launch(void* const* d_in, const int* in_sizes, int n_in,
                              void* d_out, int out_size, void* d_ws, size_t ws_size,
                              hipStream_t stream) {
    const float* X = (const float*)d_in[0];
    const int* labels = (const int*)d_in[1];

    float* sq = (float*)d_ws;                                 // N floats
    unsigned short* Xhi = (unsigned short*)(sq + N);          // N*D bf16
    unsigned short* Xlo = Xhi + (size_t)N * D;                // N*D bf16
    float* pmaxv = (float*)(Xlo + (size_t)N * D);             // N*NS2
    float* pminv = pmaxv + (size_t)N * NS2;
    int* pmaxi = (int*)(pminv + (size_t)N * NS2);
    int* pmini = pmaxi + (size_t)N * NS2;
    float* bsum = (float*)(pmini + (size_t)N * NS2);          // N/4
    int* bcnt = (int*)(bsum + N / 4);
    float* out = (float*)d_out;

    k_split_sq<<<N / 4, 256, 0, stream>>>(X, Xhi, Xlo, sq);
    k_tile_mfma<<<dim3(N / 128, N / 128), 256, 0, stream>>>(Xhi, Xlo, labels, sq,
                                                            pmaxv, pmaxi, pminv, pmini);
    k_final<<<N / 4, 256, 0, stream>>>(X, pmaxv, pmaxi, pminv, pmini, bsum, bcnt);
    k_out<<<1, 256, 0, stream>>>(bsum, bcnt, out);
}